// Round 4
// baseline (125.074 us; speedup 1.0000x reference)
//
#include <hip/hip_runtime.h>
#include <hip/hip_bf16.h>

typedef __attribute__((ext_vector_type(8))) short short8;
typedef __attribute__((ext_vector_type(4))) float f32x4;

__device__ __forceinline__ float bf2f(unsigned short b){
    union { unsigned u; float f; } uf; uf.u = ((unsigned)b) << 16; return uf.f;
}
__device__ __forceinline__ unsigned short f2bf(float f){
    union { float f; unsigned u; } uf; uf.f = f;
    unsigned u = uf.u;
    u += 0x7FFFu + ((u >> 16) & 1u);   // RNE
    return (unsigned short)(u >> 16);
}
__device__ __forceinline__ int pack2(float a, float b){
    return (int)((unsigned)f2bf(a) | ((unsigned)f2bf(b) << 16));
}

#define N_SPATIAL 1600
#define ATTN_SCALE 0.17677669529663687f  /* 32^-0.5 */

// ---------------- K1: x f32 (B,C,N) -> x_t bf16 (B,N,C) ----------------
__global__ __launch_bounds__(256) void k_xt(const float* __restrict__ x,
                                            unsigned short* __restrict__ x_t){
    int bi = blockIdx.x;              // B*50
    int b = bi / 50, nc = bi % 50;
    int n0 = nc * 32;
    int c = threadIdx.x;              // 0..255
    unsigned short vals[32];
    const float* src = x + ((size_t)(b*256 + c))*N_SPATIAL + n0;
    #pragma unroll
    for (int j=0;j<8;j++){
        float4 f = *reinterpret_cast<const float4*>(src + j*4);
        vals[j*4+0] = f2bf(f.x); vals[j*4+1] = f2bf(f.y);
        vals[j*4+2] = f2bf(f.z); vals[j*4+3] = f2bf(f.w);
    }
    unsigned short* dst = x_t + ((size_t)b*N_SPATIAL + n0)*256 + c;
    #pragma unroll
    for (int j=0;j<32;j++) dst[(size_t)j*256] = vals[j];   // coalesced across lanes
}

// ---------------- K2: v = x + BN(dwconv3x3(x)) , bf16 (B,C,N) ----------------
__global__ __launch_bounds__(256) void k_pev(const float* __restrict__ x,
                                             const float* __restrict__ pw,
                                             const float* __restrict__ pg,
                                             const float* __restrict__ pb,
                                             const float* __restrict__ pm,
                                             const float* __restrict__ pv,
                                             unsigned short* __restrict__ v){
    int idx = blockIdx.x*256 + threadIdx.x;      // < 4*256*1600
    int n  = idx % N_SPATIAL;
    int bc = idx / N_SPATIAL;
    int c  = bc & 255;
    int h = n / 40, w = n % 40;
    const float* xp = x + (size_t)bc*N_SPATIAL;
    float acc = 0.f;
    #pragma unroll
    for (int kh=-1; kh<=1; kh++){
        int hh = h + kh; if ((unsigned)hh >= 40u) continue;
        #pragma unroll
        for (int kw=-1; kw<=1; kw++){
            int ww = w + kw; if ((unsigned)ww >= 40u) continue;
            acc += xp[hh*40+ww] * pw[c*9 + (kh+1)*3 + (kw+1)];
        }
    }
    float inv = pg[c] * rsqrtf(pv[c] + 1e-5f);
    float out = xp[n] + acc*inv + (pb[c] - pm[c]*inv);
    v[idx] = f2bf(out);
}

// ---------------- K3: qkv = SiLU(BN(W @ X)) -> qk_t[b][grp][n][d], grp=o>>5 ----------------
__global__ __launch_bounds__(256) void k_qkv(const unsigned short* __restrict__ x_t,
                                             const float* __restrict__ wq,
                                             const float* __restrict__ g,
                                             const float* __restrict__ be,
                                             const float* __restrict__ mu,
                                             const float* __restrict__ va,
                                             unsigned short* __restrict__ qk_t){
    __shared__ alignas(16) unsigned short a_lds[64*32];
    __shared__ alignas(16) unsigned short b_lds[64*32];
    int bi = blockIdx.x;                      // 4*8*25
    int b = bi / 200, ot = (bi/25) % 8, nt = bi % 25;
    int o0 = ot*64, n0 = nt*64;
    int tid = threadIdx.x, w = tid>>6, lane = tid&63;
    int row = tid>>2, col8 = (tid&3)*8;
    f32x4 acc[4];
    #pragma unroll
    for (int t=0;t<4;t++) acc[t] = (f32x4){0.f,0.f,0.f,0.f};
    const float* asrc = wq + (size_t)(o0+row)*256 + col8;
    const unsigned short* bsrc = x_t + ((size_t)b*N_SPATIAL + n0 + row)*256 + col8;
    for (int k0=0; k0<256; k0+=32){
        float4 f0 = *reinterpret_cast<const float4*>(asrc + k0);
        float4 f1 = *reinterpret_cast<const float4*>(asrc + k0 + 4);
        int4 av; av.x = pack2(f0.x,f0.y); av.y = pack2(f0.z,f0.w);
                 av.z = pack2(f1.x,f1.y); av.w = pack2(f1.z,f1.w);
        *reinterpret_cast<int4*>(&a_lds[row*32 + col8]) = av;
        *reinterpret_cast<int4*>(&b_lds[row*32 + col8]) = *reinterpret_cast<const int4*>(bsrc + k0);
        __syncthreads();
        short8 af = *reinterpret_cast<const short8*>(&a_lds[(16*w + (lane&15))*32 + (lane>>4)*8]);
        #pragma unroll
        for (int t=0;t<4;t++){
            short8 bf = *reinterpret_cast<const short8*>(&b_lds[(16*t + (lane&15))*32 + (lane>>4)*8]);
            acc[t] = __builtin_amdgcn_mfma_f32_16x16x32_bf16(af, bf, acc[t], 0, 0, 0);
        }
        __syncthreads();
    }
    #pragma unroll
    for (int r=0;r<4;r++){
        int o = o0 + 16*w + (lane>>4)*4 + r;
        float inv = g[o] * rsqrtf(va[o] + 1e-5f);
        float b2  = be[o] - mu[o]*inv;
        int grp = o >> 5, d = o & 31;
        unsigned short* dst = qk_t + ((size_t)(b*16 + grp)*N_SPATIAL)*32 + d;
        #pragma unroll
        for (int t=0;t<4;t++){
            int n = n0 + 16*t + (lane&15);
            float z = acc[t][r]*inv + b2;
            float y = z / (1.f + __expf(-z));
            dst[(size_t)n*32] = f2bf(y);
        }
    }
}

// ---------------- K4: flash attention, block = (b, h, 64-row q tile) ----------------
__global__ __launch_bounds__(256) void k_attn(const unsigned short* __restrict__ qk_t,
                                              const unsigned short* __restrict__ v,
                                              unsigned short* __restrict__ ao_t){
    __shared__ alignas(16) unsigned short q_lds[64*32];
    __shared__ alignas(16) unsigned short k_lds[64*32];
    __shared__ alignas(16) unsigned short v_lds[32*72];        // [d][key] padded
    __shared__ alignas(16) unsigned short p_lds[4][16*72];     // per-wave P tile, padded
    int bi = blockIdx.x;                  // 4*8*25
    int b = bi / 200, h = (bi/25) % 8, qt = bi % 25;
    int nq0 = qt*64;
    int tid = threadIdx.x, w = tid>>6, lane = tid&63;
    int row = tid>>2, col8 = (tid&3)*8;
    int vd = tid>>3, vj = (tid&7)*8;

    *reinterpret_cast<int4*>(&q_lds[row*32 + col8]) =
        *reinterpret_cast<const int4*>(qk_t + ((size_t)(b*16 + h)*N_SPATIAL + nq0 + row)*32 + col8);

    float M[4], S[4];
    f32x4 oacc[2];
    #pragma unroll
    for (int r=0;r<4;r++){ M[r] = -1e30f; S[r] = 0.f; }
    oacc[0] = (f32x4){0.f,0.f,0.f,0.f}; oacc[1] = (f32x4){0.f,0.f,0.f,0.f};

    const unsigned short* ksrc = qk_t + ((size_t)(b*16 + 8 + h)*N_SPATIAL)*32;
    const unsigned short* vsrc = v + ((size_t)(b*256 + h*32))*N_SPATIAL;

    for (int kt=0; kt<25; kt++){
        int kb = kt*64;
        *reinterpret_cast<int4*>(&k_lds[row*32 + col8]) =
            *reinterpret_cast<const int4*>(ksrc + (size_t)(kb + row)*32 + col8);
        *reinterpret_cast<int4*>(&v_lds[vd*72 + vj]) =
            *reinterpret_cast<const int4*>(vsrc + (size_t)vd*N_SPATIAL + kb + vj);
        __syncthreads();

        short8 qf = *reinterpret_cast<const short8*>(&q_lds[(16*w + (lane&15))*32 + (lane>>4)*8]);
        f32x4 sc[4];
        #pragma unroll
        for (int t=0;t<4;t++){
            short8 kf = *reinterpret_cast<const short8*>(&k_lds[(16*t + (lane&15))*32 + (lane>>4)*8]);
            f32x4 z = (f32x4){0.f,0.f,0.f,0.f};
            sc[t] = __builtin_amdgcn_mfma_f32_16x16x32_bf16(qf, kf, z, 0, 0, 0);
        }
        #pragma unroll
        for (int t=0;t<4;t++)
            #pragma unroll
            for (int r=0;r<4;r++) sc[t][r] *= ATTN_SCALE;

        #pragma unroll
        for (int r=0;r<4;r++){
            float m = fmaxf(fmaxf(sc[0][r], sc[1][r]), fmaxf(sc[2][r], sc[3][r]));
            m = fmaxf(m, __shfl_xor(m, 1));
            m = fmaxf(m, __shfl_xor(m, 2));
            m = fmaxf(m, __shfl_xor(m, 4));
            m = fmaxf(m, __shfl_xor(m, 8));
            float mn = fmaxf(M[r], m);
            float al = __expf(M[r] - mn);
            M[r] = mn;
            float p0 = __expf(sc[0][r]-mn), p1 = __expf(sc[1][r]-mn);
            float p2 = __expf(sc[2][r]-mn), p3 = __expf(sc[3][r]-mn);
            float ts = p0+p1+p2+p3;
            ts += __shfl_xor(ts, 1);
            ts += __shfl_xor(ts, 2);
            ts += __shfl_xor(ts, 4);
            ts += __shfl_xor(ts, 8);
            S[r] = S[r]*al + ts;
            oacc[0][r] *= al; oacc[1][r] *= al;
            int prow = ((lane>>4)*4 + r)*72 + (lane&15);
            p_lds[w][prow +  0] = f2bf(p0);
            p_lds[w][prow + 16] = f2bf(p1);
            p_lds[w][prow + 32] = f2bf(p2);
            p_lds[w][prow + 48] = f2bf(p3);
        }
        // PV: out[16q][32d] += P(16x64) @ V(64x32)
        #pragma unroll
        for (int kbk=0;kbk<2;kbk++){
            short8 pf = *reinterpret_cast<const short8*>(&p_lds[w][(lane&15)*72 + kbk*32 + (lane>>4)*8]);
            #pragma unroll
            for (int f=0; f<2; f++){
                short8 vf = *reinterpret_cast<const short8*>(&v_lds[(16*f + (lane&15))*72 + kbk*32 + (lane>>4)*8]);
                oacc[f] = __builtin_amdgcn_mfma_f32_16x16x32_bf16(pf, vf, oacc[f], 0, 0, 0);
            }
        }
        __syncthreads();
    }
    #pragma unroll
    for (int f=0; f<2; f++)
        #pragma unroll
        for (int r=0;r<4;r++){
            int q = nq0 + 16*w + (lane>>4)*4 + r;
            int d = 16*f + (lane&15);
            float y = oacc[f][r] / S[r];
            ao_t[((size_t)b*N_SPATIAL + q)*256 + h*32 + d] = f2bf(y);
        }
}

// ---------------- K5: out = SiLU(BN(proj_w @ AO)) -> FLOAT32 out ----------------
__global__ __launch_bounds__(256) void k_proj(const unsigned short* __restrict__ ao_t,
                                              const float* __restrict__ wp,
                                              const float* __restrict__ g,
                                              const float* __restrict__ be,
                                              const float* __restrict__ mu,
                                              const float* __restrict__ va,
                                              float* __restrict__ out){
    __shared__ alignas(16) unsigned short a_lds[64*32];
    __shared__ alignas(16) unsigned short b_lds[64*32];
    int bi = blockIdx.x;                      // 4*4*25
    int b = bi / 100, ot = (bi/25) % 4, nt = bi % 25;
    int o0 = ot*64, n0 = nt*64;
    int tid = threadIdx.x, w = tid>>6, lane = tid&63;
    int row = tid>>2, col8 = (tid&3)*8;
    f32x4 acc[4];
    #pragma unroll
    for (int t=0;t<4;t++) acc[t] = (f32x4){0.f,0.f,0.f,0.f};
    const float* asrc = wp + (size_t)(o0+row)*256 + col8;
    const unsigned short* bsrc = ao_t + ((size_t)b*N_SPATIAL + n0 + row)*256 + col8;
    for (int k0=0; k0<256; k0+=32){
        float4 f0 = *reinterpret_cast<const float4*>(asrc + k0);
        float4 f1 = *reinterpret_cast<const float4*>(asrc + k0 + 4);
        int4 av; av.x = pack2(f0.x,f0.y); av.y = pack2(f0.z,f0.w);
                 av.z = pack2(f1.x,f1.y); av.w = pack2(f1.z,f1.w);
        *reinterpret_cast<int4*>(&a_lds[row*32 + col8]) = av;
        *reinterpret_cast<int4*>(&b_lds[row*32 + col8]) = *reinterpret_cast<const int4*>(bsrc + k0);
        __syncthreads();
        short8 af = *reinterpret_cast<const short8*>(&a_lds[(16*w + (lane&15))*32 + (lane>>4)*8]);
        #pragma unroll
        for (int t=0;t<4;t++){
            short8 bf = *reinterpret_cast<const short8*>(&b_lds[(16*t + (lane&15))*32 + (lane>>4)*8]);
            acc[t] = __builtin_amdgcn_mfma_f32_16x16x32_bf16(af, bf, acc[t], 0, 0, 0);
        }
        __syncthreads();
    }
    #pragma unroll
    for (int r=0;r<4;r++){
        int o = o0 + 16*w + (lane>>4)*4 + r;
        float inv = g[o] * rsqrtf(va[o] + 1e-5f);
        float b2  = be[o] - mu[o]*inv;
        float* dst = out + ((size_t)(b*256 + o))*N_SPATIAL;
        #pragma unroll
        for (int t=0;t<4;t++){
            int n = n0 + 16*t + (lane&15);
            float z = acc[t][r]*inv + b2;
            float y = z / (1.f + __expf(-z));
            dst[n] = y;
        }
    }
}

extern "C" void kernel_launch(void* const* d_in, const int* in_sizes, int n_in,
                              void* d_out, int out_size, void* d_ws, size_t ws_size,
                              hipStream_t stream) {
    const float* x      = (const float*)d_in[0];
    const float* qkv_w  = (const float*)d_in[1];
    const float* qkv_g  = (const float*)d_in[2];
    const float* qkv_b  = (const float*)d_in[3];
    const float* qkv_m  = (const float*)d_in[4];
    const float* qkv_v  = (const float*)d_in[5];
    const float* proj_w = (const float*)d_in[6];
    const float* proj_g = (const float*)d_in[7];
    const float* proj_b = (const float*)d_in[8];
    const float* proj_m = (const float*)d_in[9];
    const float* proj_v = (const float*)d_in[10];
    const float* pe_w   = (const float*)d_in[11];
    const float* pe_g   = (const float*)d_in[12];
    const float* pe_b   = (const float*)d_in[13];
    const float* pe_m   = (const float*)d_in[14];
    const float* pe_v   = (const float*)d_in[15];

    char* ws = (char*)d_ws;
    unsigned short* x_t  = (unsigned short*)(ws);
    unsigned short* vbuf = (unsigned short*)(ws + 3276800);
    unsigned short* qk_t = (unsigned short*)(ws + 2*3276800);
    unsigned short* ao_t = (unsigned short*)(ws + 2*3276800 + 6553600);
    float* outp = (float*)d_out;

    k_xt  <<<200, 256, 0, stream>>>(x, x_t);
    k_pev <<<6400,256, 0, stream>>>(x, pe_w, pe_g, pe_b, pe_m, pe_v, vbuf);
    k_qkv <<<800, 256, 0, stream>>>(x_t, qkv_w, qkv_g, qkv_b, qkv_m, qkv_v, qk_t);
    k_attn<<<800, 256, 0, stream>>>(qk_t, vbuf, ao_t);
    k_proj<<<400, 256, 0, stream>>>(ao_t, proj_w, proj_g, proj_b, proj_m, proj_v, outp);
}

// Round 5
// 89.932 us; speedup vs baseline: 1.3908x; 1.3908x over previous
//
#include <hip/hip_runtime.h>
#include <hip/hip_bf16.h>

typedef __attribute__((ext_vector_type(8))) short short8;
typedef __attribute__((ext_vector_type(4))) float f32x4;

__device__ __forceinline__ float bf2f(unsigned short b){
    union { unsigned u; float f; } uf; uf.u = ((unsigned)b) << 16; return uf.f;
}
__device__ __forceinline__ unsigned short f2bf(float f){
    union { float f; unsigned u; } uf; uf.f = f;
    unsigned u = uf.u;
    u += 0x7FFFu + ((u >> 16) & 1u);   // RNE
    return (unsigned short)(u >> 16);
}
__device__ __forceinline__ int pack2(float a, float b){
    return (int)((unsigned)f2bf(a) | ((unsigned)f2bf(b) << 16));
}
__device__ __forceinline__ unsigned cvtpk(float lo, float hi){
    unsigned r;
    asm("v_cvt_pk_bf16_f32 %0, %1, %2" : "=v"(r) : "v"(lo), "v"(hi));
    return r;
}
__device__ __forceinline__ f32x4 vmax4(f32x4 a, f32x4 b){
    f32x4 r; r[0]=fmaxf(a[0],b[0]); r[1]=fmaxf(a[1],b[1]);
    r[2]=fmaxf(a[2],b[2]); r[3]=fmaxf(a[3],b[3]); return r;
}

#define N_SPATIAL 1600
#define ATTN_SCALE 0.17677669529663687f  /* 32^-0.5 */

// ---------------- K1: x f32 (B,C,N) -> x_t bf16 (B,N,C) ----------------
__global__ __launch_bounds__(256) void k_xt(const float* __restrict__ x,
                                            unsigned short* __restrict__ x_t){
    int bi = blockIdx.x;              // B*50
    int b = bi / 50, nc = bi % 50;
    int n0 = nc * 32;
    int c = threadIdx.x;              // 0..255
    unsigned short vals[32];
    const float* src = x + ((size_t)(b*256 + c))*N_SPATIAL + n0;
    #pragma unroll
    for (int j=0;j<8;j++){
        float4 f = *reinterpret_cast<const float4*>(src + j*4);
        vals[j*4+0] = f2bf(f.x); vals[j*4+1] = f2bf(f.y);
        vals[j*4+2] = f2bf(f.z); vals[j*4+3] = f2bf(f.w);
    }
    unsigned short* dst = x_t + ((size_t)b*N_SPATIAL + n0)*256 + c;
    #pragma unroll
    for (int j=0;j<32;j++) dst[(size_t)j*256] = vals[j];
}

// ---------------- K2: v = x + BN(dwconv3x3(x)) , bf16 (B,C,N) ----------------
__global__ __launch_bounds__(256) void k_pev(const float* __restrict__ x,
                                             const float* __restrict__ pw,
                                             const float* __restrict__ pg,
                                             const float* __restrict__ pb,
                                             const float* __restrict__ pm,
                                             const float* __restrict__ pv,
                                             unsigned short* __restrict__ v){
    int idx = blockIdx.x*256 + threadIdx.x;      // < 4*256*1600
    int n  = idx % N_SPATIAL;
    int bc = idx / N_SPATIAL;
    int c  = bc & 255;
    int h = n / 40, w = n % 40;
    const float* xp = x + (size_t)bc*N_SPATIAL;
    float acc = 0.f;
    #pragma unroll
    for (int kh=-1; kh<=1; kh++){
        int hh = h + kh; if ((unsigned)hh >= 40u) continue;
        #pragma unroll
        for (int kw=-1; kw<=1; kw++){
            int ww = w + kw; if ((unsigned)ww >= 40u) continue;
            acc += xp[hh*40+ww] * pw[c*9 + (kh+1)*3 + (kw+1)];
        }
    }
    float inv = pg[c] * rsqrtf(pv[c] + 1e-5f);
    float out = xp[n] + acc*inv + (pb[c] - pm[c]*inv);
    v[idx] = f2bf(out);
}

// ---------------- K3: qkv = SiLU(BN(W @ X)) -> qk_t[b][grp][n][d], grp=o>>5 ----------------
__global__ __launch_bounds__(256) void k_qkv(const unsigned short* __restrict__ x_t,
                                             const float* __restrict__ wq,
                                             const float* __restrict__ g,
                                             const float* __restrict__ be,
                                             const float* __restrict__ mu,
                                             const float* __restrict__ va,
                                             unsigned short* __restrict__ qk_t){
    __shared__ alignas(16) unsigned short a_lds[64*32];
    __shared__ alignas(16) unsigned short b_lds[64*32];
    int bi = blockIdx.x;                      // 4*8*25
    int b = bi / 200, ot = (bi/25) % 8, nt = bi % 25;
    int o0 = ot*64, n0 = nt*64;
    int tid = threadIdx.x, w = tid>>6, lane = tid&63;
    int row = tid>>2, col8 = (tid&3)*8;
    f32x4 acc[4];
    #pragma unroll
    for (int t=0;t<4;t++) acc[t] = (f32x4){0.f,0.f,0.f,0.f};
    const float* asrc = wq + (size_t)(o0+row)*256 + col8;
    const unsigned short* bsrc = x_t + ((size_t)b*N_SPATIAL + n0 + row)*256 + col8;
    for (int k0=0; k0<256; k0+=32){
        float4 f0 = *reinterpret_cast<const float4*>(asrc + k0);
        float4 f1 = *reinterpret_cast<const float4*>(asrc + k0 + 4);
        int4 av; av.x = pack2(f0.x,f0.y); av.y = pack2(f0.z,f0.w);
                 av.z = pack2(f1.x,f1.y); av.w = pack2(f1.z,f1.w);
        *reinterpret_cast<int4*>(&a_lds[row*32 + col8]) = av;
        *reinterpret_cast<int4*>(&b_lds[row*32 + col8]) = *reinterpret_cast<const int4*>(bsrc + k0);
        __syncthreads();
        short8 af = *reinterpret_cast<const short8*>(&a_lds[(16*w + (lane&15))*32 + (lane>>4)*8]);
        #pragma unroll
        for (int t=0;t<4;t++){
            short8 bf = *reinterpret_cast<const short8*>(&b_lds[(16*t + (lane&15))*32 + (lane>>4)*8]);
            acc[t] = __builtin_amdgcn_mfma_f32_16x16x32_bf16(af, bf, acc[t], 0, 0, 0);
        }
        __syncthreads();
    }
    #pragma unroll
    for (int r=0;r<4;r++){
        int o = o0 + 16*w + (lane>>4)*4 + r;
        float inv = g[o] * rsqrtf(va[o] + 1e-5f);
        float b2  = be[o] - mu[o]*inv;
        int grp = o >> 5, d = o & 31;
        unsigned short* dst = qk_t + ((size_t)(b*16 + grp)*N_SPATIAL)*32 + d;
        #pragma unroll
        for (int t=0;t<4;t++){
            int n = n0 + 16*t + (lane&15);
            float z = acc[t][r]*inv + b2;
            float y = z / (1.f + __expf(-z));
            dst[(size_t)n*32] = f2bf(y);
        }
    }
}

// ---------------- K4 v2: flash attention, swapped-QK^T, split-K ----------------
// grid = 800*nsplit; block 256 (4 waves x 16q). LDS: only V double-buffer [32][72].
__global__ __launch_bounds__(256) void k_attn2(const unsigned short* __restrict__ qk_t,
                                               const unsigned short* __restrict__ v,
                                               unsigned short* __restrict__ ao_t,
                                               float* __restrict__ po,
                                               float* __restrict__ pm,
                                               float* __restrict__ ps,
                                               int nsplit, int tps){
    __shared__ alignas(16) unsigned short v_lds[2][32*72];
    int bi = blockIdx.x;
    int s  = bi / 800, qb = bi - s*800;
    int b = qb/200, h = (qb/25)%8, qt = qb%25;
    int nq0 = qt*64;
    int tid = threadIdx.x, w = tid>>6, lane = tid&63;
    int ql = lane&15, g = lane>>4;

    const unsigned short* qsrc = qk_t + ((size_t)(b*16+h)*N_SPATIAL)*32;
    const unsigned short* ksrc = qk_t + ((size_t)(b*16+8+h)*N_SPATIAL)*32;
    const unsigned short* vsrc = v + ((size_t)(b*256+h*32))*N_SPATIAL;

    // Q fragment (B-operand: col=q=lane&15, k=d=g*8..+7)
    short8 qf = *reinterpret_cast<const short8*>(qsrc + (size_t)(nq0 + w*16 + ql)*32 + g*8);

    int kt0 = s*tps, kt1 = kt0+tps; if (kt1 > 25) kt1 = 25;

    // V staging map: thread -> (d=tid>>3, 8 keys at (tid&7)*8)
    int sd = tid>>3, sc8 = (tid&7)*8;
    const unsigned short* vstage = vsrc + (size_t)sd*N_SPATIAL + sc8;
    { int4 sv = *reinterpret_cast<const int4*>(vstage + kt0*64);
      *reinterpret_cast<int4*>(&v_lds[0][sd*72 + sc8]) = sv; }
    __syncthreads();

    float M = -1e30f, S = 0.f;
    f32x4 o0 = (f32x4){0.f,0.f,0.f,0.f};
    f32x4 o1 = (f32x4){0.f,0.f,0.f,0.f};
    int bufp = 0;

    for (int kt = kt0; kt < kt1; ++kt){
        int kb = kt*64;
        bool more = (kt+1 < kt1);
        int4 sv;
        if (more) sv = *reinterpret_cast<const int4*>(vstage + (kb+64));

        // ---- QK^T (swapped): sc[t] = K_tile^T-frag x Q -> S^T[key][q]
        const unsigned short* kp = ksrc + (size_t)(kb + ql)*32 + g*8;
        short8 kf0 = *reinterpret_cast<const short8*>(kp);
        short8 kf1 = *reinterpret_cast<const short8*>(kp + 16*32);
        short8 kf2 = *reinterpret_cast<const short8*>(kp + 32*32);
        short8 kf3 = *reinterpret_cast<const short8*>(kp + 48*32);
        f32x4 z = (f32x4){0.f,0.f,0.f,0.f};
        f32x4 p0 = __builtin_amdgcn_mfma_f32_16x16x32_bf16(kf0, qf, z, 0,0,0);
        f32x4 p1 = __builtin_amdgcn_mfma_f32_16x16x32_bf16(kf1, qf, z, 0,0,0);
        f32x4 p2 = __builtin_amdgcn_mfma_f32_16x16x32_bf16(kf2, qf, z, 0,0,0);
        f32x4 p3 = __builtin_amdgcn_mfma_f32_16x16x32_bf16(kf3, qf, z, 0,0,0);

        // ---- online softmax over 64 keys for q=lane&15 (raw scores; scale folded in exp)
        f32x4 mm = vmax4(vmax4(p0,p1), vmax4(p2,p3));
        float mx = fmaxf(fmaxf(mm[0],mm[1]), fmaxf(mm[2],mm[3]));
        mx = fmaxf(mx, __shfl_xor(mx, 16));
        mx = fmaxf(mx, __shfl_xor(mx, 32));
        float mn = fmaxf(M, mx);
        float al = __expf(ATTN_SCALE*(M - mn));
        float nb = -ATTN_SCALE*mn;
        #pragma unroll
        for (int r=0;r<4;r++){
            p0[r] = __expf(fmaf(p0[r], ATTN_SCALE, nb));
            p1[r] = __expf(fmaf(p1[r], ATTN_SCALE, nb));
            p2[r] = __expf(fmaf(p2[r], ATTN_SCALE, nb));
            p3[r] = __expf(fmaf(p3[r], ATTN_SCALE, nb));
        }
        float ts = ((p0[0]+p0[1])+(p0[2]+p0[3])) + ((p1[0]+p1[1])+(p1[2]+p1[3]))
                 + ((p2[0]+p2[1])+(p2[2]+p2[3])) + ((p3[0]+p3[1])+(p3[2]+p3[3]));
        ts += __shfl_xor(ts, 16);
        ts += __shfl_xor(ts, 32);
        S = S*al + ts;
        M = mn;
        o0 *= al; o1 *= al;

        // ---- pack P^T to bf16 B-fragments (slot map shared with V reads)
        union { int4 i; short8 sv; } pb0, pb1;
        pb0.i = make_int4((int)cvtpk(p0[0],p0[1]), (int)cvtpk(p0[2],p0[3]),
                          (int)cvtpk(p1[0],p1[1]), (int)cvtpk(p1[2],p1[3]));
        pb1.i = make_int4((int)cvtpk(p2[0],p2[1]), (int)cvtpk(p2[2],p2[3]),
                          (int)cvtpk(p3[0],p3[1]), (int)cvtpk(p3[2],p3[3]));

        // ---- PV^T: out^T[d][q] += V^T-frag x P^T ; V slots {16t+4g+r}
        const unsigned short* vr0 = &v_lds[bufp][(size_t)ql*72];
        const unsigned short* vr1 = &v_lds[bufp][(size_t)(16+ql)*72];
        {
            uint2 a0 = *reinterpret_cast<const uint2*>(vr0 + 4*g);
            uint2 a1 = *reinterpret_cast<const uint2*>(vr0 + 16 + 4*g);
            union { int4 i; short8 sv; } vf; vf.i = make_int4((int)a0.x,(int)a0.y,(int)a1.x,(int)a1.y);
            o0 = __builtin_amdgcn_mfma_f32_16x16x32_bf16(vf.sv, pb0.sv, o0, 0,0,0);
            uint2 b0 = *reinterpret_cast<const uint2*>(vr0 + 32 + 4*g);
            uint2 b1 = *reinterpret_cast<const uint2*>(vr0 + 48 + 4*g);
            vf.i = make_int4((int)b0.x,(int)b0.y,(int)b1.x,(int)b1.y);
            o0 = __builtin_amdgcn_mfma_f32_16x16x32_bf16(vf.sv, pb1.sv, o0, 0,0,0);
        }
        {
            uint2 a0 = *reinterpret_cast<const uint2*>(vr1 + 4*g);
            uint2 a1 = *reinterpret_cast<const uint2*>(vr1 + 16 + 4*g);
            union { int4 i; short8 sv; } vf; vf.i = make_int4((int)a0.x,(int)a0.y,(int)a1.x,(int)a1.y);
            o1 = __builtin_amdgcn_mfma_f32_16x16x32_bf16(vf.sv, pb0.sv, o1, 0,0,0);
            uint2 b0 = *reinterpret_cast<const uint2*>(vr1 + 32 + 4*g);
            uint2 b1 = *reinterpret_cast<const uint2*>(vr1 + 48 + 4*g);
            vf.i = make_int4((int)b0.x,(int)b0.y,(int)b1.x,(int)b1.y);
            o1 = __builtin_amdgcn_mfma_f32_16x16x32_bf16(vf.sv, pb1.sv, o1, 0,0,0);
        }

        if (more){
            *reinterpret_cast<int4*>(&v_lds[bufp^1][sd*72 + sc8]) = sv;
            __syncthreads();
            bufp ^= 1;
        }
    }

    // epilogue: out row d = 16F + 4g + r, col q = lane&15
    if (nsplit == 1){
        float inv = 1.f / S;
        size_t rowoff = ((size_t)b*N_SPATIAL + nq0 + w*16 + ql)*256 + h*32;
        uint2 w0 = make_uint2((unsigned)pack2(o0[0]*inv, o0[1]*inv),
                              (unsigned)pack2(o0[2]*inv, o0[3]*inv));
        *reinterpret_cast<uint2*>(ao_t + rowoff + 4*g) = w0;
        uint2 w1 = make_uint2((unsigned)pack2(o1[0]*inv, o1[1]*inv),
                              (unsigned)pack2(o1[2]*inv, o1[3]*inv));
        *reinterpret_cast<uint2*>(ao_t + rowoff + 16 + 4*g) = w1;
    } else {
        float* op = po + ((size_t)bi*64 + w*16 + ql)*32;
        *reinterpret_cast<f32x4*>(op + 4*g) = o0;
        *reinterpret_cast<f32x4*>(op + 16 + 4*g) = o1;
        if (g == 0){
            pm[(size_t)bi*64 + w*16 + ql] = M;
            ps[(size_t)bi*64 + w*16 + ql] = S;
        }
    }
}

// ---------------- K4b: combine split-K partials ----------------
__global__ __launch_bounds__(256) void k_comb(const float* __restrict__ po,
                                              const float* __restrict__ pm,
                                              const float* __restrict__ ps,
                                              unsigned short* __restrict__ ao_t,
                                              int nsplit){
    int qb = blockIdx.x;                 // 800
    int b = qb/200, h = (qb/25)%8, qt = qb%25;
    int t = threadIdx.x;
    int q = t>>2, d0 = (t&3)*8;
    float mg = -1e30f;
    for (int s=0; s<nsplit; s++)
        mg = fmaxf(mg, pm[((size_t)s*800 + qb)*64 + q]);
    float den = 0.f;
    float acc[8];
    #pragma unroll
    for (int j=0;j<8;j++) acc[j]=0.f;
    for (int s=0; s<nsplit; s++){
        size_t idx = ((size_t)s*800 + qb)*64 + q;
        float f = __expf(ATTN_SCALE*(pm[idx] - mg));
        den += f * ps[idx];
        const float* op = po + idx*32 + d0;
        float4 a = *reinterpret_cast<const float4*>(op);
        float4 c = *reinterpret_cast<const float4*>(op + 4);
        acc[0] += f*a.x; acc[1] += f*a.y; acc[2] += f*a.z; acc[3] += f*a.w;
        acc[4] += f*c.x; acc[5] += f*c.y; acc[6] += f*c.z; acc[7] += f*c.w;
    }
    float inv = 1.f/den;
    int4 outw;
    outw.x = pack2(acc[0]*inv, acc[1]*inv);
    outw.y = pack2(acc[2]*inv, acc[3]*inv);
    outw.z = pack2(acc[4]*inv, acc[5]*inv);
    outw.w = pack2(acc[6]*inv, acc[7]*inv);
    *reinterpret_cast<int4*>(ao_t + ((size_t)b*N_SPATIAL + qt*64 + q)*256 + h*32 + d0) = outw;
}

// ---------------- K5: out = SiLU(BN(proj_w @ AO)) -> FLOAT32 out ----------------
__global__ __launch_bounds__(256) void k_proj(const unsigned short* __restrict__ ao_t,
                                              const float* __restrict__ wp,
                                              const float* __restrict__ g,
                                              const float* __restrict__ be,
                                              const float* __restrict__ mu,
                                              const float* __restrict__ va,
                                              float* __restrict__ out){
    __shared__ alignas(16) unsigned short a_lds[64*32];
    __shared__ alignas(16) unsigned short b_lds[64*32];
    int bi = blockIdx.x;                      // 4*4*25
    int b = bi / 100, ot = (bi/25) % 4, nt = bi % 25;
    int o0 = ot*64, n0 = nt*64;
    int tid = threadIdx.x, w = tid>>6, lane = tid&63;
    int row = tid>>2, col8 = (tid&3)*8;
    f32x4 acc[4];
    #pragma unroll
    for (int t=0;t<4;t++) acc[t] = (f32x4){0.f,0.f,0.f,0.f};
    const float* asrc = wp + (size_t)(o0+row)*256 + col8;
    const unsigned short* bsrc = ao_t + ((size_t)b*N_SPATIAL + n0 + row)*256 + col8;
    for (int k0=0; k0<256; k0+=32){
        float4 f0 = *reinterpret_cast<const float4*>(asrc + k0);
        float4 f1 = *reinterpret_cast<const float4*>(asrc + k0 + 4);
        int4 av; av.x = pack2(f0.x,f0.y); av.y = pack2(f0.z,f0.w);
                 av.z = pack2(f1.x,f1.y); av.w = pack2(f1.z,f1.w);
        *reinterpret_cast<int4*>(&a_lds[row*32 + col8]) = av;
        *reinterpret_cast<int4*>(&b_lds[row*32 + col8]) = *reinterpret_cast<const int4*>(bsrc + k0);
        __syncthreads();
        short8 af = *reinterpret_cast<const short8*>(&a_lds[(16*w + (lane&15))*32 + (lane>>4)*8]);
        #pragma unroll
        for (int t=0;t<4;t++){
            short8 bf = *reinterpret_cast<const short8*>(&b_lds[(16*t + (lane&15))*32 + (lane>>4)*8]);
            acc[t] = __builtin_amdgcn_mfma_f32_16x16x32_bf16(af, bf, acc[t], 0, 0, 0);
        }
        __syncthreads();
    }
    #pragma unroll
    for (int r=0;r<4;r++){
        int o = o0 + 16*w + (lane>>4)*4 + r;
        float inv = g[o] * rsqrtf(va[o] + 1e-5f);
        float b2  = be[o] - mu[o]*inv;
        float* dst = out + ((size_t)(b*256 + o))*N_SPATIAL;
        #pragma unroll
        for (int t=0;t<4;t++){
            int n = n0 + 16*t + (lane&15);
            float z = acc[t][r]*inv + b2;
            float y = z / (1.f + __expf(-z));
            dst[n] = y;
        }
    }
}

extern "C" void kernel_launch(void* const* d_in, const int* in_sizes, int n_in,
                              void* d_out, int out_size, void* d_ws, size_t ws_size,
                              hipStream_t stream) {
    const float* x      = (const float*)d_in[0];
    const float* qkv_w  = (const float*)d_in[1];
    const float* qkv_g  = (const float*)d_in[2];
    const float* qkv_b  = (const float*)d_in[3];
    const float* qkv_m  = (const float*)d_in[4];
    const float* qkv_v  = (const float*)d_in[5];
    const float* proj_w = (const float*)d_in[6];
    const float* proj_g = (const float*)d_in[7];
    const float* proj_b = (const float*)d_in[8];
    const float* proj_m = (const float*)d_in[9];
    const float* proj_v = (const float*)d_in[10];
    const float* pe_w   = (const float*)d_in[11];
    const float* pe_g   = (const float*)d_in[12];
    const float* pe_b   = (const float*)d_in[13];
    const float* pe_m   = (const float*)d_in[14];
    const float* pe_v   = (const float*)d_in[15];

    char* ws = (char*)d_ws;
    unsigned short* x_t  = (unsigned short*)(ws);
    unsigned short* vbuf = (unsigned short*)(ws + 3276800);
    unsigned short* qk_t = (unsigned short*)(ws + 2*3276800);
    unsigned short* ao_t = (unsigned short*)(ws + 2*3276800 + 6553600);
    float* outp = (float*)d_out;

    const size_t base = 16384000;                 // end of bf16 intermediates
    const size_t per_split = 800ull*64*32*4 + 2ull*800*64*4;  // o + (m,s) = 6,963,200 B
    int S = 1;
    if      (ws_size >= base + 5*per_split) S = 5;
    else if (ws_size >= base + 2*per_split) S = 2;
    float* po = (float*)(ws + base);
    float* pm = (float*)(ws + base + (size_t)S*800*64*32*4);
    float* ps = pm + (size_t)S*800*64;
    int tps = (25 + S - 1)/S;

    k_xt   <<<200, 256, 0, stream>>>(x, x_t);
    k_pev  <<<6400,256, 0, stream>>>(x, pe_w, pe_g, pe_b, pe_m, pe_v, vbuf);
    k_qkv  <<<800, 256, 0, stream>>>(x_t, qkv_w, qkv_g, qkv_b, qkv_m, qkv_v, qk_t);
    k_attn2<<<800*S, 256, 0, stream>>>(qk_t, vbuf, ao_t, po, pm, ps, S, tps);
    if (S > 1)
        k_comb<<<800, 256, 0, stream>>>(po, pm, ps, ao_t, S);
    k_proj <<<400, 256, 0, stream>>>(ao_t, proj_w, proj_g, proj_b, proj_m, proj_v, outp);
}